// Round 2
// baseline (792.804 us; speedup 1.0000x reference)
//
#include <hip/hip_runtime.h>

typedef unsigned short u16;
typedef __attribute__((ext_vector_type(8))) short bf16x8v;
typedef __attribute__((ext_vector_type(4))) float f32x4v;

#define B_SZ 16384
#define F_SZ 50
#define E_SZ 64
#define D_SZ 512
#define H1_SZ 1024
#define H2_SZ 512
#define KP 4096  // padded product-layer K: (e*64+f), f padded 50->64

__device__ __forceinline__ float b2f(u16 u){
  union { unsigned int i; float f; } v; v.i = ((unsigned int)u) << 16; return v.f;
}
__device__ __forceinline__ u16 f2b(float f){
  union { float f; unsigned int i; } v; v.f = f;
  unsigned int r = v.i + 0x7FFFu + ((v.i >> 16) & 1u);
  return (u16)(r >> 16);
}

// async global->LDS, 16B/lane. g is per-lane (base + lane*16B); lds base is
// wave-uniform; HW writes lds_base + lane*16.
__device__ __forceinline__ void gload16(const u16* g, u16* lds_base_uniform){
#if __has_builtin(__builtin_amdgcn_global_load_lds)
  __builtin_amdgcn_global_load_lds(
      (const __attribute__((address_space(1))) unsigned int*)g,
      (__attribute__((address_space(3))) unsigned int*)lds_base_uniform,
      16, 0, 0);
#else
  int lane = threadIdx.x & 63;
  *(uint4*)(lds_base_uniform + lane*8) = *(const uint4*)g;
#endif
}

// ---------------- gather: embT[b][e*64+f] = fe[idx[b,f],e]*fv[b,f] (bf16), f>=50 -> 0
__global__ __launch_bounds__(256) void k_gather(
    const int* __restrict__ fidx, const float* __restrict__ fval,
    const float* __restrict__ femb, u16* __restrict__ embT)
{
  __shared__ int   sidx[F_SZ];
  __shared__ float sfv[F_SZ];
  __shared__ u16   tile[F_SZ*66];   // padded stride 66 to break bank conflicts
  const int b = blockIdx.x, t = threadIdx.x;
  if (t < F_SZ){ sidx[t] = fidx[b*F_SZ+t]; sfv[t] = fval[b*F_SZ+t]; }
  __syncthreads();
  #pragma unroll
  for (int i=0;i<13;i++){
    int k = i*256+t;
    if (k < F_SZ*E_SZ){
      int f = k>>6, e = k&63;
      tile[f*66+e] = f2b(femb[(size_t)sidx[f]*E_SZ + e] * sfv[f]);
    }
  }
  __syncthreads();
  u16* orow = embT + (size_t)b*KP;
  #pragma unroll
  for (int i=0;i<16;i++){
    int k = i*256+t;           // k = e*64+f
    int f = k&63, e = k>>6;
    orow[k] = (f < F_SZ) ? tile[f*66+e] : (u16)0;
  }
}

// ---------------- product_linear (D,F,E) fp32 -> WlT (D, e*64+f) bf16 zero-padded
__global__ __launch_bounds__(256) void k_wlt(const float* __restrict__ Wl, u16* __restrict__ WlT)
{
  __shared__ u16 tile[F_SZ*66];
  const int d = blockIdx.x, t = threadIdx.x;
  #pragma unroll
  for (int i=0;i<13;i++){
    int k = i*256+t;
    if (k < F_SZ*E_SZ) tile[(k>>6)*66 + (k&63)] = f2b(Wl[(size_t)d*(F_SZ*E_SZ) + k]);
  }
  __syncthreads();
  u16* orow = WlT + (size_t)d*KP;
  #pragma unroll
  for (int i=0;i<16;i++){
    int k = i*256+t;
    int f = k&63, e = k>>6;
    orow[k] = (f < F_SZ) ? tile[f*66+e] : (u16)0;
  }
}

// ---------------- (K,N) fp32 -> (N,K) bf16 transpose for dense weights
__global__ void k_transpose(const float* __restrict__ W, u16* __restrict__ WT,
                            int klog2, int N, int total){
  int idx = blockIdx.x*256 + threadIdx.x;
  if (idx < total){
    int k = idx & ((1<<klog2)-1), n = idx >> klog2;
    WT[idx] = f2b(W[(size_t)k*N + n]);
  }
}

// ---------------- cvec[h] = sum_d pbias[d]*W0[d][h] + b0[h]  (fp32, exact bias fold)
__global__ __launch_bounds__(256) void k_cvec(
    const float* __restrict__ pb, const float* __restrict__ W0,
    const float* __restrict__ b0, float* __restrict__ cvec)
{
  int h = blockIdx.x*256 + threadIdx.x;   // 4 blocks x 256 = 1024
  float acc = b0[h];
  for (int d=0; d<D_SZ; d++) acc += pb[d]*W0[(size_t)d*H1_SZ + h];
  cvec[h] = acc;
}

// ---------------- m97-style BT GEMM: C(MxN) = A(MxK) * Bm(NxK)^T, bf16 inputs
// DO_STATS: add fp32 bias[n], atomically accumulate per-column sum/sumsq.
// CT = u16 (bf16 store) or float (fp32 store).
template<int DO_STATS, typename CT>
__global__ __launch_bounds__(256) void gemm_bt(
    const u16* __restrict__ A, const u16* __restrict__ Bm,
    CT* __restrict__ C, const float* __restrict__ bias,
    float* __restrict__ S1, float* __restrict__ S2,
    int M, int N, int K)
{
  __shared__ __align__(16) u16 As[128*64];
  __shared__ __align__(16) u16 Bs[128*64];
  const int tid  = threadIdx.x;
  const int wave = tid >> 6, lane = tid & 63;
  const int quad = lane >> 4, l16 = lane & 15;
  const int n0 = blockIdx.x * 128, m0 = blockIdx.y * 128;
  const int wr = wave >> 1, wc = wave & 1;
  const int lr = lane >> 3, lc = (lane & 7) * 8;

  f32x4v acc[4][4];
  #pragma unroll
  for (int i=0;i<4;i++)
    #pragma unroll
    for (int j=0;j<4;j++)
      acc[i][j] = (f32x4v){0.f,0.f,0.f,0.f};

  for (int k0 = 0; k0 < K; k0 += 64){
    __syncthreads();
    #pragma unroll
    for (int c=0;c<4;c++){
      const int r0 = wave*32 + 8*c;          // 8 rows per 16B-call
      gload16(A  + (size_t)(m0 + r0 + lr)*K + k0 + lc, As + r0*64);
      gload16(Bm + (size_t)(n0 + r0 + lr)*K + k0 + lc, Bs + r0*64);
    }
    __syncthreads();
    #pragma unroll
    for (int ks=0; ks<2; ks++){
      bf16x8v af[4], bfr[4];
      #pragma unroll
      for (int mt=0;mt<4;mt++)
        af[mt] = *(const bf16x8v*)&As[(wr*64+mt*16+l16)*64 + ks*32 + quad*8];
      #pragma unroll
      for (int nt=0;nt<4;nt++)
        bfr[nt] = *(const bf16x8v*)&Bs[(wc*64+nt*16+l16)*64 + ks*32 + quad*8];
      #pragma unroll
      for (int mt=0;mt<4;mt++)
        #pragma unroll
        for (int nt=0;nt<4;nt++)
          acc[mt][nt] = __builtin_amdgcn_mfma_f32_16x16x32_bf16(af[mt], bfr[nt], acc[mt][nt], 0, 0, 0);
    }
  }

  // epilogue; C/D layout: n = lane&15, m = quad*4 + reg
  #pragma unroll
  for (int nt=0;nt<4;nt++){
    const int n = n0 + wc*64 + nt*16 + l16;
    float bv = 0.f;
    if (DO_STATS) bv = bias[n];
    float ls1 = 0.f, ls2 = 0.f;
    #pragma unroll
    for (int mt=0;mt<4;mt++){
      const int mb = m0 + wr*64 + mt*16 + quad*4;
      #pragma unroll
      for (int r=0;r<4;r++){
        float v = acc[mt][nt][r] + bv;
        if constexpr (sizeof(CT) == 2) C[(size_t)(mb+r)*N + n] = f2b(v);
        else                           C[(size_t)(mb+r)*N + n] = v;
        ls1 += v; ls2 += v*v;
      }
    }
    if (DO_STATS){
      ls1 += __shfl_xor(ls1, 16); ls2 += __shfl_xor(ls2, 16);
      ls1 += __shfl_xor(ls1, 32); ls2 += __shfl_xor(ls2, 32);
      if (quad == 0){ atomicAdd(&S1[n], ls1); atomicAdd(&S2[n], ls2); }
    }
  }
}

// ---------------- quadratic-inner: per-wave S_b = P(128x64) * E_b(64x64)^T,
// lp = ||S_b[d,:]||, y0c = relu(lz + lp + pbias) - pbias   (centered for bf16 store)
__global__ __launch_bounds__(256) void k_lp(
    const u16* __restrict__ embT, const float* __restrict__ Pq,
    const u16* __restrict__ lz, const float* __restrict__ pbias,
    u16* __restrict__ y0)
{
  __shared__ __align__(16) u16 Ap[128*64];
  __shared__ __align__(16) u16 Eb[4][64*64];
  const int tid  = threadIdx.x;
  const int wave = tid >> 6, lane = tid & 63;
  const int quad = lane >> 4, l16 = lane & 15;
  const int d0 = blockIdx.x * 128;
  const int b  = blockIdx.y * 4 + wave;

  // stage P chunk as bf16 (zero-padded f 50->64)
  #pragma unroll
  for (int i=0;i<32;i++){
    int k = i*256 + tid;       // r*64+f
    int r = k >> 6, f = k & 63;
    Ap[k] = (f < F_SZ) ? f2b(Pq[(d0 + r)*F_SZ + f]) : (u16)0;
  }
  // stage this wave's embT row (e-major, 4096 bf16, already padded)
  {
    const u16* g = embT + (size_t)b*KP + lane*8;
    #pragma unroll
    for (int c=0;c<8;c++)
      gload16(g + c*512, &Eb[wave][c*512]);
  }
  __syncthreads();

  f32x4v acc[8][4];
  #pragma unroll
  for (int i=0;i<8;i++)
    #pragma unroll
    for (int j=0;j<4;j++)
      acc[i][j] = (f32x4v){0.f,0.f,0.f,0.f};

  bf16x8v bfr[2][4];
  #pragma unroll
  for (int ks=0;ks<2;ks++)
    #pragma unroll
    for (int nt=0;nt<4;nt++)
      bfr[ks][nt] = *(const bf16x8v*)&Eb[wave][(nt*16+l16)*64 + ks*32 + quad*8];

  #pragma unroll
  for (int mt=0;mt<8;mt++){
    bf16x8v a0 = *(const bf16x8v*)&Ap[(mt*16+l16)*64 +      quad*8];
    bf16x8v a1 = *(const bf16x8v*)&Ap[(mt*16+l16)*64 + 32 + quad*8];
    #pragma unroll
    for (int nt=0;nt<4;nt++){
      acc[mt][nt] = __builtin_amdgcn_mfma_f32_16x16x32_bf16(a0, bfr[0][nt], acc[mt][nt],0,0,0);
      acc[mt][nt] = __builtin_amdgcn_mfma_f32_16x16x32_bf16(a1, bfr[1][nt], acc[mt][nt],0,0,0);
    }
  }

  #pragma unroll
  for (int mt=0;mt<8;mt++){
    float s[4] = {0.f,0.f,0.f,0.f};
    #pragma unroll
    for (int nt=0;nt<4;nt++)
      #pragma unroll
      for (int r=0;r<4;r++)
        s[r] += acc[mt][nt][r]*acc[mt][nt][r];
    #pragma unroll
    for (int r=0;r<4;r++){                 // sum 16 e-columns (within quad)
      s[r] += __shfl_xor(s[r],1);
      s[r] += __shfl_xor(s[r],2);
      s[r] += __shfl_xor(s[r],4);
      s[r] += __shfl_xor(s[r],8);
    }
    if (l16 == 0){
      #pragma unroll
      for (int r=0;r<4;r++){
        int d = d0 + mt*16 + quad*4 + r;
        float pbv = pbias[d];
        float v = b2f(lz[(size_t)b*D_SZ + d]) + sqrtf(s[r]) + pbv;
        v = v > 0.f ? v : 0.f;
        y0[(size_t)b*D_SZ + d] = f2b(v - pbv);
      }
    }
  }
}

// ---------------- BN finalize: per-column scale/offset from sums
__global__ void k_bnfin(const float* __restrict__ S1, const float* __restrict__ S2, int n,
                        const float* __restrict__ bnsc, const float* __restrict__ bnof,
                        float* __restrict__ Aout, float* __restrict__ Bout)
{
  int i = blockIdx.x*256 + threadIdx.x;
  if (i < n){
    const float invB = 1.f / 16384.f;
    float m   = S1[i]*invB;
    float var = S2[i]*invB - m*m;
    float a   = bnsc[0] * rsqrtf(var + 1e-10f);
    Aout[i] = a;
    Bout[i] = bnof[0] - m*a;
  }
}

// ---------------- BN apply + relu: fp32 Z in, bf16 Y out, 8 elems/thread
__global__ __launch_bounds__(256) void k_bnapply(
    const float* __restrict__ Z, u16* __restrict__ Y,
    const float* __restrict__ Aa, const float* __restrict__ Bb, int nmask)
{
  size_t base = ((size_t)blockIdx.x*256 + threadIdx.x) * 8;
  int n0 = (int)(base & (size_t)nmask);
  float4 za = *(const float4*)&Z[base];
  float4 zb = *(const float4*)&Z[base+4];
  float zz[8] = {za.x,za.y,za.z,za.w,zb.x,zb.y,zb.z,zb.w};
  union { uint4 q; u16 s[8]; } o;
  #pragma unroll
  for (int j=0;j<8;j++){
    float v = zz[j] * Aa[n0+j] + Bb[n0+j];
    o.s[j] = f2b(v > 0.f ? v : 0.f);
  }
  *(uint4*)&Y[base] = o.q;
}

// ---------------- final dot + sigmoid, one wave per row; fp32 w and out
__global__ __launch_bounds__(256) void k_out(
    const u16* __restrict__ Y2, const float* __restrict__ wvec,
    const float* __restrict__ obp, float* __restrict__ out)
{
  const int wave = threadIdx.x >> 6, lane = threadIdx.x & 63;
  const int b = blockIdx.x*4 + wave;
  union { uint4 q; u16 s[8]; } y;
  y.q = *(const uint4*)&Y2[(size_t)b*H2_SZ + lane*8];
  float4 wa = *(const float4*)&wvec[lane*8];
  float4 wb = *(const float4*)&wvec[lane*8+4];
  float wv[8] = {wa.x,wa.y,wa.z,wa.w,wb.x,wb.y,wb.z,wb.w};
  float s = 0.f;
  #pragma unroll
  for (int j=0;j<8;j++) s += b2f(y.s[j]) * wv[j];
  s += __shfl_xor(s,1);  s += __shfl_xor(s,2);  s += __shfl_xor(s,4);
  s += __shfl_xor(s,8);  s += __shfl_xor(s,16); s += __shfl_xor(s,32);
  if (lane == 0){
    float x = s + obp[0];
    out[b] = 1.f / (1.f + expf(-x));
  }
}

// ---------------- workspace map (bytes) ----------------
// embT  @ 0          : 16384*4096*2 = 134217728   (dead after k_lp; reused:)
//   z1  @ 0          : 16384*1024*4 =  67108864   (fp32 pre-BN layer0)
//   y1  @ 67108864   : 16384*1024*2 =  33554432   (bf16 post-BN layer0)
//   z2  @ 100663296  : 16384*512*4  =  33554432   (fp32 pre-BN layer1)
// WlT   @ 134217728  : 4194304
// W0T   @ 138412032  : 1048576
// W1T   @ 139460608  : 1048576
// lz    @ 140509184  : 16777216    (dead after k_lp; reused as y2 bf16)
// y0    @ 157286400  : 16777216    (bf16, bias-centered)
// stats @ 174063616  : S1a[1024] S2a[1024] S1b[512] S2b[512] (zeroed, 12288 B)
//                      A0[1024] B0[1024] A1[512] B1[512] cvec[1024] (written)
// total ~ 174.1 MB

extern "C" void kernel_launch(void* const* d_in, const int* in_sizes, int n_in,
                              void* d_out, int out_size, void* d_ws, size_t ws_size,
                              hipStream_t stream)
{
  const int*   fidx  = (const int*)d_in[0];
  const float* fval  = (const float*)d_in[1];
  const float* femb  = (const float*)d_in[2];
  const float* wl    = (const float*)d_in[3];
  const float* pbias = (const float*)d_in[4];
  const float* pq    = (const float*)d_in[5];
  const float* w0    = (const float*)d_in[6];
  const float* b0    = (const float*)d_in[7];
  const float* w1    = (const float*)d_in[8];
  const float* b1    = (const float*)d_in[9];
  const float* bnsc  = (const float*)d_in[10];
  const float* bnof  = (const float*)d_in[11];
  const float* ow    = (const float*)d_in[12];
  const float* ob    = (const float*)d_in[13];
  float* out = (float*)d_out;

  char* ws = (char*)d_ws;
  u16*   embT = (u16*)(ws + 0);
  float* z1b  = (float*)(ws + 0);
  u16*   y1b  = (u16*)(ws + 67108864);
  float* z2b  = (float*)(ws + 100663296);
  u16*   wlT  = (u16*)(ws + 134217728);
  u16*   w0T  = (u16*)(ws + 138412032);
  u16*   w1T  = (u16*)(ws + 139460608);
  u16*   lzb  = (u16*)(ws + 140509184);
  u16*   y2b  = (u16*)(ws + 140509184);
  u16*   y0b  = (u16*)(ws + 157286400);
  float* S1a  = (float*)(ws + 174063616);
  float* S2a  = S1a + 1024;
  float* S1b  = S2a + 1024;
  float* S2b  = S1b + 512;
  float* A0   = S2b + 512;
  float* B0   = A0 + 1024;
  float* A1   = B0 + 1024;
  float* B1   = A1 + 512;
  float* cvec = B1 + 512;

  hipMemsetAsync((void*)S1a, 0, 12288, stream);

  k_gather<<<B_SZ, 256, 0, stream>>>(fidx, fval, femb, embT);
  k_wlt<<<D_SZ, 256, 0, stream>>>(wl, wlT);
  k_transpose<<<2048, 256, 0, stream>>>(w0, w0T, 9, 1024, 524288);   // (512,1024)->(1024,512)
  k_transpose<<<2048, 256, 0, stream>>>(w1, w1T, 10, 512, 524288);   // (1024,512)->(512,1024)
  k_cvec<<<4, 256, 0, stream>>>(pbias, w0, b0, cvec);

  gemm_bt<0,u16><<<dim3(4,128), 256, 0, stream>>>(embT, wlT, lzb, nullptr, nullptr, nullptr,
                                                  B_SZ, D_SZ, KP);
  k_lp<<<dim3(4,4096), 256, 0, stream>>>(embT, pq, lzb, pbias, y0b);

  gemm_bt<1,float><<<dim3(8,128), 256, 0, stream>>>(y0b, w0T, z1b, cvec, S1a, S2a,
                                                    B_SZ, H1_SZ, D_SZ);
  k_bnfin<<<4, 256, 0, stream>>>(S1a, S2a, 1024, bnsc, bnof, A0, B0);
  k_bnapply<<<8192, 256, 0, stream>>>(z1b, y1b, A0, B0, 1023);

  gemm_bt<1,float><<<dim3(4,128), 256, 0, stream>>>(y1b, w1T, z2b, b1, S1b, S2b,
                                                    B_SZ, H2_SZ, H1_SZ);
  k_bnfin<<<2, 256, 0, stream>>>(S1b, S2b, 512, bnsc, bnof, A1, B1);
  k_bnapply<<<4096, 256, 0, stream>>>(z2b, y2b, A1, B1, 511);

  k_out<<<4096, 256, 0, stream>>>(y2b, ow, ob, out);
}

// Round 3
// 597.012 us; speedup vs baseline: 1.3280x; 1.3280x over previous
//
#include <hip/hip_runtime.h>

typedef unsigned short u16;
typedef __attribute__((ext_vector_type(8))) short bf16x8v;
typedef __attribute__((ext_vector_type(4))) float f32x4v;

#define B_SZ 16384
#define F_SZ 50
#define E_SZ 64
#define D_SZ 512
#define H1_SZ 1024
#define H2_SZ 512
#define KP 4096   // padded product-layer K: (e*64+f), f padded 50->64
#define LP_NB 32  // b's per k_lp block; grid = B_SZ/LP_NB = 512

__device__ __forceinline__ float b2f(u16 u){
  union { unsigned int i; float f; } v; v.i = ((unsigned int)u) << 16; return v.f;
}
__device__ __forceinline__ u16 f2b(float f){
  union { float f; unsigned int i; } v; v.f = f;
  unsigned int r = v.i + 0x7FFFu + ((v.i >> 16) & 1u);
  return (u16)(r >> 16);
}

// async global->LDS, 16B/lane. g is per-lane (base + lane*16B); lds base is
// wave-uniform; HW writes lds_base + lane*16.
__device__ __forceinline__ void gload16(const u16* g, u16* lds_base_uniform){
#if __has_builtin(__builtin_amdgcn_global_load_lds)
  __builtin_amdgcn_global_load_lds(
      (const __attribute__((address_space(1))) unsigned int*)g,
      (__attribute__((address_space(3))) unsigned int*)lds_base_uniform,
      16, 0, 0);
#else
  int lane = threadIdx.x & 63;
  *(uint4*)(lds_base_uniform + lane*8) = *(const uint4*)g;
#endif
}

// ---------------- gather: embT[b][e*64+f] = fe[idx[b,f],e]*fv[b,f] (bf16), f>=50 -> 0
__global__ __launch_bounds__(256) void k_gather(
    const int* __restrict__ fidx, const float* __restrict__ fval,
    const float* __restrict__ femb, u16* __restrict__ embT)
{
  __shared__ int   sidx[F_SZ];
  __shared__ float sfv[F_SZ];
  __shared__ u16   tile[F_SZ*66];   // padded stride 66 to break bank conflicts
  const int b = blockIdx.x, t = threadIdx.x;
  if (t < F_SZ){ sidx[t] = fidx[b*F_SZ+t]; sfv[t] = fval[b*F_SZ+t]; }
  __syncthreads();
  #pragma unroll
  for (int i=0;i<13;i++){
    int k = i*256+t;
    if (k < F_SZ*E_SZ){
      int f = k>>6, e = k&63;
      tile[f*66+e] = f2b(femb[(size_t)sidx[f]*E_SZ + e] * sfv[f]);
    }
  }
  __syncthreads();
  u16* orow = embT + (size_t)b*KP;
  #pragma unroll
  for (int i=0;i<16;i++){
    int k = i*256+t;           // k = e*64+f
    int f = k&63, e = k>>6;
    orow[k] = (f < F_SZ) ? tile[f*66+e] : (u16)0;
  }
}

// ---------------- product_linear (D,F,E) fp32 -> WlT (D, e*64+f) bf16 zero-padded
__global__ __launch_bounds__(256) void k_wlt(const float* __restrict__ Wl, u16* __restrict__ WlT)
{
  __shared__ u16 tile[F_SZ*66];
  const int d = blockIdx.x, t = threadIdx.x;
  #pragma unroll
  for (int i=0;i<13;i++){
    int k = i*256+t;
    if (k < F_SZ*E_SZ) tile[(k>>6)*66 + (k&63)] = f2b(Wl[(size_t)d*(F_SZ*E_SZ) + k]);
  }
  __syncthreads();
  u16* orow = WlT + (size_t)d*KP;
  #pragma unroll
  for (int i=0;i<16;i++){
    int k = i*256+t;
    int f = k&63, e = k>>6;
    orow[k] = (f < F_SZ) ? tile[f*66+e] : (u16)0;
  }
}

// ---------------- product_quadratic_inner (D,F) fp32 -> PqTp (D,64) bf16 padded
__global__ void k_pqt(const float* __restrict__ Pq, u16* __restrict__ PqTp){
  int idx = blockIdx.x*256 + threadIdx.x;   // grid 128 -> 32768
  int d = idx >> 6, f = idx & 63;
  PqTp[idx] = (f < F_SZ) ? f2b(Pq[d*F_SZ + f]) : (u16)0;
}

// ---------------- (K,N) fp32 -> (N,K) bf16 transpose for dense weights
__global__ void k_transpose(const float* __restrict__ W, u16* __restrict__ WT,
                            int klog2, int N, int total){
  int idx = blockIdx.x*256 + threadIdx.x;
  if (idx < total){
    int k = idx & ((1<<klog2)-1), n = idx >> klog2;
    WT[idx] = f2b(W[(size_t)k*N + n]);
  }
}

// ---------------- cvec[h] = sum_d pbias[d]*W0[d][h] + b0[h]  (fp32, exact bias fold)
__global__ __launch_bounds__(256) void k_cvec(
    const float* __restrict__ pb, const float* __restrict__ W0,
    const float* __restrict__ b0, float* __restrict__ cvec)
{
  int h = blockIdx.x*256 + threadIdx.x;   // 4 blocks x 256 = 1024
  float acc = b0[h];
  for (int d=0; d<D_SZ; d++) acc += pb[d]*W0[(size_t)d*H1_SZ + h];
  cvec[h] = acc;
}

// ---------------- m97-style BT GEMM: C(MxN) = A(MxK) * Bm(NxK)^T, bf16 inputs
// DO_STATS: add fp32 bias[n], atomically accumulate per-column sum/sumsq.
template<int DO_STATS, typename CT>
__global__ __launch_bounds__(256) void gemm_bt(
    const u16* __restrict__ A, const u16* __restrict__ Bm,
    CT* __restrict__ C, const float* __restrict__ bias,
    float* __restrict__ S1, float* __restrict__ S2,
    int M, int N, int K)
{
  __shared__ __align__(16) u16 As[128*64];
  __shared__ __align__(16) u16 Bs[128*64];
  const int tid  = threadIdx.x;
  const int wave = tid >> 6, lane = tid & 63;
  const int quad = lane >> 4, l16 = lane & 15;
  const int n0 = blockIdx.x * 128, m0 = blockIdx.y * 128;
  const int wr = wave >> 1, wc = wave & 1;
  const int lr = lane >> 3, lc = (lane & 7) * 8;

  f32x4v acc[4][4];
  #pragma unroll
  for (int i=0;i<4;i++)
    #pragma unroll
    for (int j=0;j<4;j++)
      acc[i][j] = (f32x4v){0.f,0.f,0.f,0.f};

  for (int k0 = 0; k0 < K; k0 += 64){
    __syncthreads();
    #pragma unroll
    for (int c=0;c<4;c++){
      const int r0 = wave*32 + 8*c;          // 8 rows per 16B-call
      gload16(A  + (size_t)(m0 + r0 + lr)*K + k0 + lc, As + r0*64);
      gload16(Bm + (size_t)(n0 + r0 + lr)*K + k0 + lc, Bs + r0*64);
    }
    __syncthreads();
    #pragma unroll
    for (int ks=0; ks<2; ks++){
      bf16x8v af[4], bfr[4];
      #pragma unroll
      for (int mt=0;mt<4;mt++)
        af[mt] = *(const bf16x8v*)&As[(wr*64+mt*16+l16)*64 + ks*32 + quad*8];
      #pragma unroll
      for (int nt=0;nt<4;nt++)
        bfr[nt] = *(const bf16x8v*)&Bs[(wc*64+nt*16+l16)*64 + ks*32 + quad*8];
      #pragma unroll
      for (int mt=0;mt<4;mt++)
        #pragma unroll
        for (int nt=0;nt<4;nt++)
          acc[mt][nt] = __builtin_amdgcn_mfma_f32_16x16x32_bf16(af[mt], bfr[nt], acc[mt][nt], 0, 0, 0);
    }
  }

  // epilogue; C/D layout: n = lane&15, m = quad*4 + reg
  #pragma unroll
  for (int nt=0;nt<4;nt++){
    const int n = n0 + wc*64 + nt*16 + l16;
    float bv = 0.f;
    if (DO_STATS) bv = bias[n];
    float ls1 = 0.f, ls2 = 0.f;
    #pragma unroll
    for (int mt=0;mt<4;mt++){
      const int mb = m0 + wr*64 + mt*16 + quad*4;
      #pragma unroll
      for (int r=0;r<4;r++){
        float v = acc[mt][nt][r] + bv;
        if constexpr (sizeof(CT) == 2) C[(size_t)(mb+r)*N + n] = f2b(v);
        else                           C[(size_t)(mb+r)*N + n] = v;
        ls1 += v; ls2 += v*v;
      }
    }
    if (DO_STATS){
      ls1 += __shfl_xor(ls1, 16); ls2 += __shfl_xor(ls2, 16);
      ls1 += __shfl_xor(ls1, 32); ls2 += __shfl_xor(ls2, 32);
      if (quad == 0){ atomicAdd(&S1[n], ls1); atomicAdd(&S2[n], ls2); }
    }
  }
}

// ---------------- quadratic-inner, restructured.
// Per block: stage all of PqTp (512x64 bf16, 64 KB) once; loop LP_NB batches
// with double-buffered embT rows. Tiles computed TRANSPOSED: rows=e, cols=d
// (A-operand = embT row, M=64 e; B-operand = PqTp, N=128 d per wave), so the
// sum over e runs over (quad,reg) -> 16 FMAs + 2 shuffles per 16 d.
// y0c = relu(lz + ||S|| + pbias) - pbias  (bias-centered for bf16 store)
__global__ __launch_bounds__(256) void k_lp(
    const u16* __restrict__ embT, const u16* __restrict__ PqTp,
    const u16* __restrict__ lz, const float* __restrict__ pbias,
    u16* __restrict__ y0)
{
  __shared__ __align__(16) u16 Ps[D_SZ*64];    // 64 KB, whole P^T
  __shared__ __align__(16) u16 Eb[2][64*64];   // 2 x 8 KB double buffer
  const int tid  = threadIdx.x;
  const int wave = tid >> 6, lane = tid & 63;
  const int quad = lane >> 4, l16 = lane & 15;
  const int b0    = blockIdx.x * LP_NB;
  const int dbase = wave * 128;                // wave covers d in [dbase, dbase+128)

  // stage P^T once: each wave stages its own 128 rows (16 KB = 16 calls)
  {
    const u16* g = PqTp + dbase*64 + lane*8;
    u16* l = Ps + dbase*64;
    #pragma unroll
    for (int c=0;c<16;c++) gload16(g + c*512, l + c*512);
  }
  // stage Eb[0] for b0 (8 KB; each wave 2 KB)
  {
    const u16* g = embT + (size_t)b0*KP + wave*1024 + lane*8;
    gload16(g,       Eb[0] + wave*1024);
    gload16(g + 512, Eb[0] + wave*1024 + 512);
  }
  __syncthreads();

  for (int i=0; i<LP_NB; i++){
    const int b   = b0 + i;
    const int cur = i & 1;
    if (i+1 < LP_NB){
      const u16* g = embT + (size_t)(b+1)*KP + wave*1024 + lane*8;
      gload16(g,       Eb[cur^1] + wave*1024);
      gload16(g + 512, Eb[cur^1] + wave*1024 + 512);
    }

    f32x4v acc[4][8];
    #pragma unroll
    for (int mt=0;mt<4;mt++)
      #pragma unroll
      for (int nt=0;nt<8;nt++)
        acc[mt][nt] = (f32x4v){0.f,0.f,0.f,0.f};

    #pragma unroll
    for (int ks=0;ks<2;ks++){
      bf16x8v af[4];
      #pragma unroll
      for (int mt=0;mt<4;mt++)
        af[mt] = *(const bf16x8v*)&Eb[cur][(mt*16+l16)*64 + ks*32 + quad*8];
      #pragma unroll
      for (int nt=0;nt<8;nt++){
        bf16x8v bfr = *(const bf16x8v*)&Ps[(dbase + nt*16 + l16)*64 + ks*32 + quad*8];
        #pragma unroll
        for (int mt=0;mt<4;mt++)
          acc[mt][nt] = __builtin_amdgcn_mfma_f32_16x16x32_bf16(af[mt], bfr, acc[mt][nt], 0, 0, 0);
      }
    }

    // reduction over e = over (quad, reg): 16 FMAs + 2 shuffles per d-tile
    float v[8];
    #pragma unroll
    for (int nt=0;nt<8;nt++){
      float s = 0.f;
      #pragma unroll
      for (int mt=0;mt<4;mt++)
        #pragma unroll
        for (int r=0;r<4;r++)
          s = fmaf(acc[mt][nt][r], acc[mt][nt][r], s);
      s += __shfl_xor(s, 16);
      s += __shfl_xor(s, 32);
      v[nt] = s;                   // lp^2 for d = dbase + nt*16 + l16 (all lanes)
    }
    // lane handles d0 = dbase+lane (v[quad]) and d1 = dbase+64+lane (v[quad+4])
    float t01 = (quad & 1) ? v[1] : v[0];
    float t23 = (quad & 1) ? v[3] : v[2];
    float vlo = (quad & 2) ? t23 : t01;
    float t45 = (quad & 1) ? v[5] : v[4];
    float t67 = (quad & 1) ? v[7] : v[6];
    float vhi = (quad & 2) ? t67 : t45;

    const int d0i = dbase + lane, d1i = d0i + 64;
    float pb0v = pbias[d0i], pb1v = pbias[d1i];
    float lz0 = b2f(lz[(size_t)b*D_SZ + d0i]);
    float lz1 = b2f(lz[(size_t)b*D_SZ + d1i]);
    float y0v = lz0 + sqrtf(vlo) + pb0v;  y0v = (y0v > 0.f ? y0v : 0.f) - pb0v;
    float y1v = lz1 + sqrtf(vhi) + pb1v;  y1v = (y1v > 0.f ? y1v : 0.f) - pb1v;
    y0[(size_t)b*D_SZ + d0i] = f2b(y0v);
    y0[(size_t)b*D_SZ + d1i] = f2b(y1v);

    __syncthreads();   // drain prefetch; protect Eb[cur] before overwrite at i+2
  }
}

// ---------------- BN finalize: per-column scale/offset from sums
__global__ void k_bnfin(const float* __restrict__ S1, const float* __restrict__ S2, int n,
                        const float* __restrict__ bnsc, const float* __restrict__ bnof,
                        float* __restrict__ Aout, float* __restrict__ Bout)
{
  int i = blockIdx.x*256 + threadIdx.x;
  if (i < n){
    const float invB = 1.f / 16384.f;
    float m   = S1[i]*invB;
    float var = S2[i]*invB - m*m;
    float a   = bnsc[0] * rsqrtf(var + 1e-10f);
    Aout[i] = a;
    Bout[i] = bnof[0] - m*a;
  }
}

// ---------------- BN apply + relu: fp32 Z in, bf16 Y out, 8 elems/thread
__global__ __launch_bounds__(256) void k_bnapply(
    const float* __restrict__ Z, u16* __restrict__ Y,
    const float* __restrict__ Aa, const float* __restrict__ Bb, int nmask)
{
  size_t base = ((size_t)blockIdx.x*256 + threadIdx.x) * 8;
  int n0 = (int)(base & (size_t)nmask);
  float4 za = *(const float4*)&Z[base];
  float4 zb = *(const float4*)&Z[base+4];
  float zz[8] = {za.x,za.y,za.z,za.w,zb.x,zb.y,zb.z,zb.w};
  union { uint4 q; u16 s[8]; } o;
  #pragma unroll
  for (int j=0;j<8;j++){
    float v = zz[j] * Aa[n0+j] + Bb[n0+j];
    o.s[j] = f2b(v > 0.f ? v : 0.f);
  }
  *(uint4*)&Y[base] = o.q;
}

// ---------------- final dot + sigmoid, one wave per row; fp32 w and out
__global__ __launch_bounds__(256) void k_out(
    const u16* __restrict__ Y2, const float* __restrict__ wvec,
    const float* __restrict__ obp, float* __restrict__ out)
{
  const int wave = threadIdx.x >> 6, lane = threadIdx.x & 63;
  const int b = blockIdx.x*4 + wave;
  union { uint4 q; u16 s[8]; } y;
  y.q = *(const uint4*)&Y2[(size_t)b*H2_SZ + lane*8];
  float4 wa = *(const float4*)&wvec[lane*8];
  float4 wb = *(const float4*)&wvec[lane*8+4];
  float wv[8] = {wa.x,wa.y,wa.z,wa.w,wb.x,wb.y,wb.z,wb.w};
  float s = 0.f;
  #pragma unroll
  for (int j=0;j<8;j++) s += b2f(y.s[j]) * wv[j];
  s += __shfl_xor(s,1);  s += __shfl_xor(s,2);  s += __shfl_xor(s,4);
  s += __shfl_xor(s,8);  s += __shfl_xor(s,16); s += __shfl_xor(s,32);
  if (lane == 0){
    float x = s + obp[0];
    out[b] = 1.f / (1.f + expf(-x));
  }
}

// ---------------- workspace map (bytes) ----------------
// embT  @ 0          : 134217728   (dead after k_lp; reused:)
//   z1  @ 0          :  67108864   (fp32 pre-BN layer0)
//   y1  @ 67108864   :  33554432   (bf16 post-BN layer0)
//   z2  @ 100663296  :  33554432   (fp32 pre-BN layer1)
// WlT   @ 134217728  :   4194304
// W0T   @ 138412032  :   1048576
// W1T   @ 139460608  :   1048576
// lz    @ 140509184  :  16777216   (dead after k_lp; reused as y2 bf16)
// y0    @ 157286400  :  16777216   (bf16, bias-centered)
// stats @ 174063616  : S1a/S2a/S1b/S2b (12288, zeroed) + A0/B0/A1/B1/cvec (16384)
// PqTp  @ 174096384  :     65536
// total ~ 174.2 MB

extern "C" void kernel_launch(void* const* d_in, const int* in_sizes, int n_in,
                              void* d_out, int out_size, void* d_ws, size_t ws_size,
                              hipStream_t stream)
{
  const int*   fidx  = (const int*)d_in[0];
  const float* fval  = (const float*)d_in[1];
  const float* femb  = (const float*)d_in[2];
  const float* wl    = (const float*)d_in[3];
  const float* pbias = (const float*)d_in[4];
  const float* pq    = (const float*)d_in[5];
  const float* w0    = (const float*)d_in[6];
  const float* b0    = (const float*)d_in[7];
  const float* w1    = (const float*)d_in[8];
  const float* b1    = (const float*)d_in[9];
  const float* bnsc  = (const float*)d_in[10];
  const float* bnof  = (const float*)d_in[11];
  const float* ow    = (const float*)d_in[12];
  const float* ob    = (const float*)d_in[13];
  float* out = (float*)d_out;

  char* ws = (char*)d_ws;
  u16*   embT = (u16*)(ws + 0);
  float* z1b  = (float*)(ws + 0);
  u16*   y1b  = (u16*)(ws + 67108864);
  float* z2b  = (float*)(ws + 100663296);
  u16*   wlT  = (u16*)(ws + 134217728);
  u16*   w0T  = (u16*)(ws + 138412032);
  u16*   w1T  = (u16*)(ws + 139460608);
  u16*   lzb  = (u16*)(ws + 140509184);
  u16*   y2b  = (u16*)(ws + 140509184);
  u16*   y0b  = (u16*)(ws + 157286400);
  float* S1a  = (float*)(ws + 174063616);
  float* S2a  = S1a + 1024;
  float* S1b  = S2a + 1024;
  float* S2b  = S1b + 512;
  float* A0   = S2b + 512;
  float* B0   = A0 + 1024;
  float* A1   = B0 + 1024;
  float* B1   = A1 + 512;
  float* cvec = B1 + 512;
  u16*   pqT  = (u16*)(ws + 174096384);

  hipMemsetAsync((void*)S1a, 0, 12288, stream);

  k_gather<<<B_SZ, 256, 0, stream>>>(fidx, fval, femb, embT);
  k_wlt<<<D_SZ, 256, 0, stream>>>(wl, wlT);
  k_pqt<<<128, 256, 0, stream>>>(pq, pqT);
  k_transpose<<<2048, 256, 0, stream>>>(w0, w0T, 9, 1024, 524288);   // (512,1024)->(1024,512)
  k_transpose<<<2048, 256, 0, stream>>>(w1, w1T, 10, 512, 524288);   // (1024,512)->(512,1024)
  k_cvec<<<4, 256, 0, stream>>>(pbias, w0, b0, cvec);

  gemm_bt<0,u16><<<dim3(4,128), 256, 0, stream>>>(embT, wlT, lzb, nullptr, nullptr, nullptr,
                                                  B_SZ, D_SZ, KP);
  k_lp<<<B_SZ/LP_NB, 256, 0, stream>>>(embT, pqT, lzb, pbias, y0b);

  gemm_bt<1,float><<<dim3(8,128), 256, 0, stream>>>(y0b, w0T, z1b, cvec, S1a, S2a,
                                                    B_SZ, H1_SZ, D_SZ);
  k_bnfin<<<4, 256, 0, stream>>>(S1a, S2a, 1024, bnsc, bnof, A0, B0);
  k_bnapply<<<8192, 256, 0, stream>>>(z1b, y1b, A0, B0, 1023);

  gemm_bt<1,float><<<dim3(4,128), 256, 0, stream>>>(y1b, w1T, z2b, b1, S1b, S2b,
                                                    B_SZ, H2_SZ, H1_SZ);
  k_bnfin<<<2, 256, 0, stream>>>(S1b, S2b, 512, bnsc, bnof, A1, B1);
  k_bnapply<<<4096, 256, 0, stream>>>(z2b, y2b, A1, B1, 511);

  k_out<<<4096, 256, 0, stream>>>(y2b, ow, ob, out);
}

// Round 4
// 548.241 us; speedup vs baseline: 1.4461x; 1.0890x over previous
//
#include <hip/hip_runtime.h>

typedef unsigned short u16;
typedef __attribute__((ext_vector_type(8))) short bf16x8v;
typedef __attribute__((ext_vector_type(4))) float f32x4v;

#define B_SZ 16384
#define F_SZ 50
#define E_SZ 64
#define D_SZ 512
#define H1_SZ 1024
#define H2_SZ 512
#define KP 4096   // padded product-layer K: (e*64+f), f padded 50->64
#define LP_NB 16  // b's per k_lp block; grid = (2, B_SZ/LP_NB)

__device__ __forceinline__ float b2f(u16 u){
  union { unsigned int i; float f; } v; v.i = ((unsigned int)u) << 16; return v.f;
}
__device__ __forceinline__ u16 f2b(float f){
  union { float f; unsigned int i; } v; v.f = f;
  unsigned int r = v.i + 0x7FFFu + ((v.i >> 16) & 1u);
  return (u16)(r >> 16);
}

// async global->LDS, 16B/lane. g is per-lane (base + lane*16B); lds base is
// wave-uniform; HW writes lds_base + lane*16.
__device__ __forceinline__ void gload16(const u16* g, u16* lds_base_uniform){
#if __has_builtin(__builtin_amdgcn_global_load_lds)
  __builtin_amdgcn_global_load_lds(
      (const __attribute__((address_space(1))) unsigned int*)g,
      (__attribute__((address_space(3))) unsigned int*)lds_base_uniform,
      16, 0, 0);
#else
  int lane = threadIdx.x & 63;
  *(uint4*)(lds_base_uniform + lane*8) = *(const uint4*)g;
#endif
}

// ---------------- gather: embT[b][e*64+f] = fe[idx[b,f],e]*fv[b,f] (bf16), f>=50 -> 0
__global__ __launch_bounds__(256) void k_gather(
    const int* __restrict__ fidx, const float* __restrict__ fval,
    const float* __restrict__ femb, u16* __restrict__ embT)
{
  __shared__ int   sidx[F_SZ];
  __shared__ float sfv[F_SZ];
  __shared__ u16   tile[F_SZ*66];   // padded stride 66 to break bank conflicts
  const int b = blockIdx.x, t = threadIdx.x;
  if (t < F_SZ){ sidx[t] = fidx[b*F_SZ+t]; sfv[t] = fval[b*F_SZ+t]; }
  __syncthreads();
  #pragma unroll
  for (int i=0;i<13;i++){
    int k = i*256+t;
    if (k < F_SZ*E_SZ){
      int f = k>>6, e = k&63;
      tile[f*66+e] = f2b(femb[(size_t)sidx[f]*E_SZ + e] * sfv[f]);
    }
  }
  __syncthreads();
  u16* orow = embT + (size_t)b*KP;
  #pragma unroll
  for (int i=0;i<16;i++){
    int k = i*256+t;           // k = e*64+f
    int f = k&63, e = k>>6;
    orow[k] = (f < F_SZ) ? tile[f*66+e] : (u16)0;
  }
}

// ---------------- product_linear (D,F,E) fp32 -> WlT (D, e*64+f) bf16 zero-padded
__global__ __launch_bounds__(256) void k_wlt(const float* __restrict__ Wl, u16* __restrict__ WlT)
{
  __shared__ u16 tile[F_SZ*66];
  const int d = blockIdx.x, t = threadIdx.x;
  #pragma unroll
  for (int i=0;i<13;i++){
    int k = i*256+t;
    if (k < F_SZ*E_SZ) tile[(k>>6)*66 + (k&63)] = f2b(Wl[(size_t)d*(F_SZ*E_SZ) + k]);
  }
  __syncthreads();
  u16* orow = WlT + (size_t)d*KP;
  #pragma unroll
  for (int i=0;i<16;i++){
    int k = i*256+t;
    int f = k&63, e = k>>6;
    orow[k] = (f < F_SZ) ? tile[f*66+e] : (u16)0;
  }
}

// ---------------- product_quadratic_inner (D,F) fp32 -> PqTp (D,64) bf16 padded
__global__ void k_pqt(const float* __restrict__ Pq, u16* __restrict__ PqTp){
  int idx = blockIdx.x*256 + threadIdx.x;   // grid 128 -> 32768
  int d = idx >> 6, f = idx & 63;
  PqTp[idx] = (f < F_SZ) ? f2b(Pq[d*F_SZ + f]) : (u16)0;
}

// ---------------- (K,N) fp32 -> (N,K) bf16 transpose for dense weights
__global__ void k_transpose(const float* __restrict__ W, u16* __restrict__ WT,
                            int klog2, int N, int total){
  int idx = blockIdx.x*256 + threadIdx.x;
  if (idx < total){
    int k = idx & ((1<<klog2)-1), n = idx >> klog2;
    WT[idx] = f2b(W[(size_t)k*N + n]);
  }
}

// ---------------- cvec[h] += sum_{d in chunk} pbias[d]*W0[d][h] (+ b0[h] once)
// grid (4, 8), block 256; cvec pre-zeroed by memset.
__global__ __launch_bounds__(256) void k_cvec(
    const float* __restrict__ pb, const float* __restrict__ W0,
    const float* __restrict__ b0, float* __restrict__ cvec)
{
  int h = blockIdx.x*256 + threadIdx.x;
  int d0 = blockIdx.y*64;
  float acc = (blockIdx.y == 0) ? b0[h] : 0.f;
  #pragma unroll 8
  for (int d=0; d<64; d++) acc += pb[d0+d]*W0[(size_t)(d0+d)*H1_SZ + h];
  atomicAdd(&cvec[h], acc);
}

// ---------------- m97-style BT GEMM: C(MxN) = A(MxK) * Bm(NxK)^T, bf16 inputs
// DO_STATS: add fp32 bias[n], atomically accumulate per-column sum/sumsq.
template<int DO_STATS, typename CT>
__global__ __launch_bounds__(256) void gemm_bt(
    const u16* __restrict__ A, const u16* __restrict__ Bm,
    CT* __restrict__ C, const float* __restrict__ bias,
    float* __restrict__ S1, float* __restrict__ S2,
    int M, int N, int K)
{
  __shared__ __align__(16) u16 As[128*64];
  __shared__ __align__(16) u16 Bs[128*64];
  const int tid  = threadIdx.x;
  const int wave = tid >> 6, lane = tid & 63;
  const int quad = lane >> 4, l16 = lane & 15;
  const int n0 = blockIdx.x * 128, m0 = blockIdx.y * 128;
  const int wr = wave >> 1, wc = wave & 1;
  const int lr = lane >> 3, lc = (lane & 7) * 8;

  f32x4v acc[4][4];
  #pragma unroll
  for (int i=0;i<4;i++)
    #pragma unroll
    for (int j=0;j<4;j++)
      acc[i][j] = (f32x4v){0.f,0.f,0.f,0.f};

  for (int k0 = 0; k0 < K; k0 += 64){
    __syncthreads();
    #pragma unroll
    for (int c=0;c<4;c++){
      const int r0 = wave*32 + 8*c;          // 8 rows per 16B-call
      gload16(A  + (size_t)(m0 + r0 + lr)*K + k0 + lc, As + r0*64);
      gload16(Bm + (size_t)(n0 + r0 + lr)*K + k0 + lc, Bs + r0*64);
    }
    __syncthreads();
    #pragma unroll
    for (int ks=0; ks<2; ks++){
      bf16x8v af[4], bfr[4];
      #pragma unroll
      for (int mt=0;mt<4;mt++)
        af[mt] = *(const bf16x8v*)&As[(wr*64+mt*16+l16)*64 + ks*32 + quad*8];
      #pragma unroll
      for (int nt=0;nt<4;nt++)
        bfr[nt] = *(const bf16x8v*)&Bs[(wc*64+nt*16+l16)*64 + ks*32 + quad*8];
      #pragma unroll
      for (int mt=0;mt<4;mt++)
        #pragma unroll
        for (int nt=0;nt<4;nt++)
          acc[mt][nt] = __builtin_amdgcn_mfma_f32_16x16x32_bf16(af[mt], bfr[nt], acc[mt][nt], 0, 0, 0);
    }
  }

  // epilogue; C/D layout: n = lane&15, m = quad*4 + reg
  #pragma unroll
  for (int nt=0;nt<4;nt++){
    const int n = n0 + wc*64 + nt*16 + l16;
    float bv = 0.f;
    if (DO_STATS) bv = bias[n];
    float ls1 = 0.f, ls2 = 0.f;
    #pragma unroll
    for (int mt=0;mt<4;mt++){
      const int mb = m0 + wr*64 + mt*16 + quad*4;
      #pragma unroll
      for (int r=0;r<4;r++){
        float v = acc[mt][nt][r] + bv;
        if constexpr (sizeof(CT) == 2) C[(size_t)(mb+r)*N + n] = f2b(v);
        else                           C[(size_t)(mb+r)*N + n] = v;
        ls1 += v; ls2 += v*v;
      }
    }
    if (DO_STATS){
      ls1 += __shfl_xor(ls1, 16); ls2 += __shfl_xor(ls2, 16);
      ls1 += __shfl_xor(ls1, 32); ls2 += __shfl_xor(ls2, 32);
      if (quad == 0){ atomicAdd(&S1[n], ls1); atomicAdd(&S2[n], ls2); }
    }
  }
}

// ---------------- quadratic-inner v3: LDS-free, register-resident P^T.
// Wave covers 64 d; block (4 waves) covers 256 d; grid (2 d-halves, B/LP_NB).
// Tiles TRANSPOSED (rows=e from embT, cols=d from PqTp); Ps fragments are
// loop-invariant (held in VGPRs); A fragments per-lane 16B global loads
// (16B-aligned; row shared by 4 waves -> L1 hits). No LDS, no barriers.
__global__ __launch_bounds__(256) void k_lp(
    const u16* __restrict__ embT, const u16* __restrict__ PqTp,
    const u16* __restrict__ lz, const float* __restrict__ pbias,
    u16* __restrict__ y0)
{
  const int tid  = threadIdx.x;
  const int wave = tid >> 6, lane = tid & 63;
  const int quad = lane >> 4, l16 = lane & 15;
  const int dwave = blockIdx.x*256 + wave*64;   // this wave's 64 d's
  const int b0    = blockIdx.y * LP_NB;

  // loop-invariant B-operand fragments (4 nt x 2 ks)
  bf16x8v ps[4][2];
  #pragma unroll
  for (int nt=0;nt<4;nt++)
    #pragma unroll
    for (int ks=0;ks<2;ks++)
      ps[nt][ks] = *(const bf16x8v*)&PqTp[(dwave + nt*16 + l16)*64 + ks*32 + quad*8];

  const int dme = dwave + lane;      // epilogue: lane -> d (coalesced)
  const float pbv = pbias[dme];

  bf16x8v afA[8], afB[8];            // A fragments, ping-pong [ks*4+mt]
  {
    const u16* g = embT + (size_t)b0*KP;
    #pragma unroll
    for (int ks=0;ks<2;ks++)
      #pragma unroll
      for (int mt=0;mt<4;mt++)
        afA[ks*4+mt] = *(const bf16x8v*)&g[(mt*16+l16)*64 + ks*32 + quad*8];
  }

  #pragma unroll 1
  for (int i=0;i<LP_NB;i+=2){
    // prefetch b0+i+1 into afB
    {
      const u16* g = embT + (size_t)(b0+i+1)*KP;
      #pragma unroll
      for (int ks=0;ks<2;ks++)
        #pragma unroll
        for (int mt=0;mt<4;mt++)
          afB[ks*4+mt] = *(const bf16x8v*)&g[(mt*16+l16)*64 + ks*32 + quad*8];
    }
    // compute for b0+i with afA
    {
      const int b = b0+i;
      float v[4];
      #pragma unroll
      for (int nt=0;nt<4;nt++){
        f32x4v acc[4];
        #pragma unroll
        for (int mt=0;mt<4;mt++) acc[mt] = (f32x4v){0.f,0.f,0.f,0.f};
        #pragma unroll
        for (int ks=0;ks<2;ks++)
          #pragma unroll
          for (int mt=0;mt<4;mt++)
            acc[mt] = __builtin_amdgcn_mfma_f32_16x16x32_bf16(afA[ks*4+mt], ps[nt][ks], acc[mt], 0,0,0);
        float s = 0.f;
        #pragma unroll
        for (int mt=0;mt<4;mt++)
          #pragma unroll
          for (int r=0;r<4;r++)
            s = fmaf(acc[mt][r], acc[mt][r], s);
        s += __shfl_xor(s, 16);
        s += __shfl_xor(s, 32);
        v[nt] = s;                   // lp^2 for d = dwave + nt*16 + l16
      }
      float t01 = (quad & 1) ? v[1] : v[0];
      float t23 = (quad & 1) ? v[3] : v[2];
      float vs  = (quad & 2) ? t23 : t01;   // lane's own d = dwave+lane
      float lzv = b2f(lz[(size_t)b*D_SZ + dme]);
      float y = lzv + sqrtf(vs) + pbv;
      y = (y > 0.f ? y : 0.f) - pbv;
      y0[(size_t)b*D_SZ + dme] = f2b(y);
    }
    // prefetch b0+i+2 into afA
    if (i+2 < LP_NB){
      const u16* g = embT + (size_t)(b0+i+2)*KP;
      #pragma unroll
      for (int ks=0;ks<2;ks++)
        #pragma unroll
        for (int mt=0;mt<4;mt++)
          afA[ks*4+mt] = *(const bf16x8v*)&g[(mt*16+l16)*64 + ks*32 + quad*8];
    }
    // compute for b0+i+1 with afB
    {
      const int b = b0+i+1;
      float v[4];
      #pragma unroll
      for (int nt=0;nt<4;nt++){
        f32x4v acc[4];
        #pragma unroll
        for (int mt=0;mt<4;mt++) acc[mt] = (f32x4v){0.f,0.f,0.f,0.f};
        #pragma unroll
        for (int ks=0;ks<2;ks++)
          #pragma unroll
          for (int mt=0;mt<4;mt++)
            acc[mt] = __builtin_amdgcn_mfma_f32_16x16x32_bf16(afB[ks*4+mt], ps[nt][ks], acc[mt], 0,0,0);
        float s = 0.f;
        #pragma unroll
        for (int mt=0;mt<4;mt++)
          #pragma unroll
          for (int r=0;r<4;r++)
            s = fmaf(acc[mt][r], acc[mt][r], s);
        s += __shfl_xor(s, 16);
        s += __shfl_xor(s, 32);
        v[nt] = s;
      }
      float t01 = (quad & 1) ? v[1] : v[0];
      float t23 = (quad & 1) ? v[3] : v[2];
      float vs  = (quad & 2) ? t23 : t01;
      float lzv = b2f(lz[(size_t)b*D_SZ + dme]);
      float y = lzv + sqrtf(vs) + pbv;
      y = (y > 0.f ? y : 0.f) - pbv;
      y0[(size_t)b*D_SZ + dme] = f2b(y);
    }
  }
}

// ---------------- BN finalize: per-column scale/offset from sums
__global__ void k_bnfin(const float* __restrict__ S1, const float* __restrict__ S2, int n,
                        const float* __restrict__ bnsc, const float* __restrict__ bnof,
                        float* __restrict__ Aout, float* __restrict__ Bout)
{
  int i = blockIdx.x*256 + threadIdx.x;
  if (i < n){
    const float invB = 1.f / 16384.f;
    float m   = S1[i]*invB;
    float var = S2[i]*invB - m*m;
    float a   = bnsc[0] * rsqrtf(var + 1e-10f);
    Aout[i] = a;
    Bout[i] = bnof[0] - m*a;
  }
}

// ---------------- BN apply + relu: fp32 Z in, bf16 Y out, 8 elems/thread
__global__ __launch_bounds__(256) void k_bnapply(
    const float* __restrict__ Z, u16* __restrict__ Y,
    const float* __restrict__ Aa, const float* __restrict__ Bb, int nmask)
{
  size_t base = ((size_t)blockIdx.x*256 + threadIdx.x) * 8;
  int n0 = (int)(base & (size_t)nmask);
  float4 za = *(const float4*)&Z[base];
  float4 zb = *(const float4*)&Z[base+4];
  float zz[8] = {za.x,za.y,za.z,za.w,zb.x,zb.y,zb.z,zb.w};
  union { uint4 q; u16 s[8]; } o;
  #pragma unroll
  for (int j=0;j<8;j++){
    float v = zz[j] * Aa[n0+j] + Bb[n0+j];
    o.s[j] = f2b(v > 0.f ? v : 0.f);
  }
  *(uint4*)&Y[base] = o.q;
}

// ---------------- final dot + sigmoid, one wave per row; fp32 w and out
__global__ __launch_bounds__(256) void k_out(
    const u16* __restrict__ Y2, const float* __restrict__ wvec,
    const float* __restrict__ obp, float* __restrict__ out)
{
  const int wave = threadIdx.x >> 6, lane = threadIdx.x & 63;
  const int b = blockIdx.x*4 + wave;
  union { uint4 q; u16 s[8]; } y;
  y.q = *(const uint4*)&Y2[(size_t)b*H2_SZ + lane*8];
  float4 wa = *(const float4*)&wvec[lane*8];
  float4 wb = *(const float4*)&wvec[lane*8+4];
  float wv[8] = {wa.x,wa.y,wa.z,wa.w,wb.x,wb.y,wb.z,wb.w};
  float s = 0.f;
  #pragma unroll
  for (int j=0;j<8;j++) s += b2f(y.s[j]) * wv[j];
  s += __shfl_xor(s,1);  s += __shfl_xor(s,2);  s += __shfl_xor(s,4);
  s += __shfl_xor(s,8);  s += __shfl_xor(s,16); s += __shfl_xor(s,32);
  if (lane == 0){
    float x = s + obp[0];
    out[b] = 1.f / (1.f + expf(-x));
  }
}

// ---------------- workspace map (bytes) ----------------
// embT  @ 0          : 134217728   (dead after k_lp; reused:)
//   z1  @ 0          :  67108864   (fp32 pre-BN layer0)
//   y1  @ 67108864   :  33554432   (bf16 post-BN layer0)
//   z2  @ 100663296  :  33554432   (fp32 pre-BN layer1)
// WlT   @ 134217728  :   4194304
// W0T   @ 138412032  :   1048576
// W1T   @ 139460608  :   1048576
// lz    @ 140509184  :  16777216   (dead after k_lp; reused as y2 bf16)
// y0    @ 157286400  :  16777216   (bf16, bias-centered)
// stats @ 174063616  : memset 16384 B: S1a[1024] S2a[1024] S1b[512] S2b[512] cvec[1024]
//                      then A0[1024] B0[1024] A1[512] B1[512] (written by bnfin)
// PqTp  @ 174096384  :     65536
// total ~ 174.2 MB

extern "C" void kernel_launch(void* const* d_in, const int* in_sizes, int n_in,
                              void* d_out, int out_size, void* d_ws, size_t ws_size,
                              hipStream_t stream)
{
  const int*   fidx  = (const int*)d_in[0];
  const float* fval  = (const float*)d_in[1];
  const float* femb  = (const float*)d_in[2];
  const float* wl    = (const float*)d_in[3];
  const float* pbias = (const float*)d_in[4];
  const float* pq    = (const float*)d_in[5];
  const float* w0    = (const float*)d_in[6];
  const float* b0    = (const float*)d_in[7];
  const float* w1    = (const float*)d_in[8];
  const float* b1    = (const float*)d_in[9];
  const float* bnsc  = (const float*)d_in[10];
  const float* bnof  = (const float*)d_in[11];
  const float* ow    = (const float*)d_in[12];
  const float* ob    = (const float*)d_in[13];
  float* out = (float*)d_out;

  char* ws = (char*)d_ws;
  u16*   embT = (u16*)(ws + 0);
  float* z1b  = (float*)(ws + 0);
  u16*   y1b  = (u16*)(ws + 67108864);
  float* z2b  = (float*)(ws + 100663296);
  u16*   wlT  = (u16*)(ws + 134217728);
  u16*   w0T  = (u16*)(ws + 138412032);
  u16*   w1T  = (u16*)(ws + 139460608);
  u16*   lzb  = (u16*)(ws + 140509184);
  u16*   y2b  = (u16*)(ws + 140509184);
  u16*   y0b  = (u16*)(ws + 157286400);
  float* S1a  = (float*)(ws + 174063616);
  float* S2a  = S1a + 1024;
  float* S1b  = S2a + 1024;
  float* S2b  = S1b + 512;
  float* cvec = S2b + 512;
  float* A0   = cvec + 1024;
  float* B0   = A0 + 1024;
  float* A1   = B0 + 1024;
  float* B1   = A1 + 512;
  u16*   pqT  = (u16*)(ws + 174096384);

  hipMemsetAsync((void*)S1a, 0, 16384, stream);   // S1a,S2a,S1b,S2b,cvec

  k_gather<<<B_SZ, 256, 0, stream>>>(fidx, fval, femb, embT);
  k_wlt<<<D_SZ, 256, 0, stream>>>(wl, wlT);
  k_pqt<<<128, 256, 0, stream>>>(pq, pqT);
  k_transpose<<<2048, 256, 0, stream>>>(w0, w0T, 9, 1024, 524288);   // (512,1024)->(1024,512)
  k_transpose<<<2048, 256, 0, stream>>>(w1, w1T, 10, 512, 524288);   // (1024,512)->(512,1024)
  k_cvec<<<dim3(4,8), 256, 0, stream>>>(pbias, w0, b0, cvec);

  gemm_bt<0,u16><<<dim3(4,128), 256, 0, stream>>>(embT, wlT, lzb, nullptr, nullptr, nullptr,
                                                  B_SZ, D_SZ, KP);
  k_lp<<<dim3(2, B_SZ/LP_NB), 256, 0, stream>>>(embT, pqT, lzb, pbias, y0b);

  gemm_bt<1,float><<<dim3(8,128), 256, 0, stream>>>(y0b, w0T, z1b, cvec, S1a, S2a,
                                                    B_SZ, H1_SZ, D_SZ);
  k_bnfin<<<4, 256, 0, stream>>>(S1a, S2a, 1024, bnsc, bnof, A0, B0);
  k_bnapply<<<8192, 256, 0, stream>>>(z1b, y1b, A0, B0, 1023);

  gemm_bt<1,float><<<dim3(4,128), 256, 0, stream>>>(y1b, w1T, z2b, b1, S1b, S2b,
                                                    B_SZ, H2_SZ, H1_SZ);
  k_bnfin<<<2, 256, 0, stream>>>(S1b, S2b, 512, bnsc, bnof, A1, B1);
  k_bnapply<<<4096, 256, 0, stream>>>(z2b, y2b, A1, B1, 511);

  k_out<<<4096, 256, 0, stream>>>(y2b, ow, ob, out);
}